// Round 4
// baseline (1270.921 us; speedup 1.0000x reference)
//
#include <hip/hip_runtime.h>
#include <math.h>

// Problem constants (B=2, L=2048, H=1024, d_inner=2048, d_state=16, d_conv=4)
#define BATCH 2
#define LSEQ  2048
#define HDIM  1024
#define DI    2048
#define DS    16
#define NPROJ 2080          // 2*DS + DI
#define TOK   4096          // BATCH*LSEQ
#define XZW   4096          // 2*DI

typedef _Float16 f16;
typedef _Float16 f16x8 __attribute__((ext_vector_type(8)));
typedef _Float16 f16x4 __attribute__((ext_vector_type(4)));
typedef float    f32x4 __attribute__((ext_vector_type(4)));

__device__ __forceinline__ float siluf(float v) { return v / (1.f + __expf(-v)); }
__device__ __forceinline__ float softplusf(float v) {
  return v > 20.f ? v : log1pf(__expf(v));
}

// async global->LDS, 16B per lane. LDS dest must be wave-uniform base + lane*16.
__device__ __forceinline__ void gload16(const void* g, void* l) {
  __builtin_amdgcn_global_load_lds(
      (const __attribute__((address_space(1))) void*)g,
      (__attribute__((address_space(3))) void*)l, 16, 0, 0);
}

// ---------------- weight transpose+cast: Wt[c][r] = (f16)W[r][c] ----------------
__global__ __launch_bounds__(256) void k_transpose(
    const float* __restrict__ W, f16* __restrict__ Wt, int R, int C) {
  __shared__ float t[32][33];
  int c0 = blockIdx.x * 32, r0 = blockIdx.y * 32;
  int tx = threadIdx.x & 31, ty = threadIdx.x >> 5;  // 32 x 8
#pragma unroll
  for (int i = 0; i < 4; ++i) {
    int r = ty + i * 8;
    t[r][tx] = W[(size_t)(r0 + r) * C + c0 + tx];
  }
  __syncthreads();
#pragma unroll
  for (int i = 0; i < 4; ++i) {
    int r = ty + i * 8;  // row in Wt tile (= col in W)
    Wt[(size_t)(c0 + r) * R + r0 + tx] = (f16)t[tx][r];
  }
}

// ---------------- RMSNorm -> f16 ----------------
__global__ __launch_bounds__(256) void k_rmsnorm(
    const float* __restrict__ x, const float* __restrict__ w, f16* __restrict__ h) {
  int t = blockIdx.x;
  int tid = threadIdx.x;
  float4 v = reinterpret_cast<const float4*>(x + (size_t)t * HDIM)[tid];
  float ss = v.x * v.x + v.y * v.y + v.z * v.z + v.w * v.w;
#pragma unroll
  for (int off = 32; off; off >>= 1) ss += __shfl_down(ss, off, 64);
  __shared__ float sred[4];
  if ((tid & 63) == 0) sred[tid >> 6] = ss;
  __syncthreads();
  float tot = sred[0] + sred[1] + sred[2] + sred[3];
  float scale = rsqrtf(tot * (1.f / HDIM) + 1e-6f);
  float4 wv = reinterpret_cast<const float4*>(w)[tid];
  f16x4 o;
  o[0] = (f16)(v.x * scale * wv.x);
  o[1] = (f16)(v.y * scale * wv.y);
  o[2] = (f16)(v.z * scale * wv.z);
  o[3] = (f16)(v.w * scale * wv.w);
  *reinterpret_cast<f16x4*>(h + (size_t)t * HDIM + tid * 4) = o;
}

// ---------------- f16 MFMA GEMM: C[M,N](f32) = A[M,K](f16) @ Bt[N,K](f16)^T ----
// 128x128 tile, BK=32, 4 waves (2x2 of 64x64), 16x16x32 MFMA, 4x4 frags/wave.
// LDS tiles [128 rows][32 k] f16, XOR-swizzled (byte ^= (row&3)<<4) via
// pre-swizzled global source feeding linear global_load_lds (m173 pattern).
// MODE 0: plain store. MODE 1: softplus cols>=32. MODE 2: += R.
template <int MODE>
__global__ __launch_bounds__(256) void k_mgemm(
    const f16* __restrict__ A, const f16* __restrict__ Bt,
    float* __restrict__ C, const float* __restrict__ R,
    int M, int N, int K) {
  __shared__ __align__(16) f16 At[128 * 32];
  __shared__ __align__(16) f16 Bs[128 * 32];
  const int tid = threadIdx.x;
  const int lane = tid & 63;
  const int w = tid >> 6;
  const int wm = w >> 1, wn = w & 1;
  const int m0 = blockIdx.y * 128, n0 = blockIdx.x * 128;
  const int Nlim = N - 1;

  f32x4 acc[4][4];
#pragma unroll
  for (int i = 0; i < 4; ++i)
#pragma unroll
    for (int j = 0; j < 4; ++j) acc[i][j] = (f32x4){0.f, 0.f, 0.f, 0.f};

  const int fr = lane & 15;          // fragment row (A row / Bt row / D col)
  const int kg = (lane >> 4) << 3;   // k element offset: 0/8/16/24

  for (int k0 = 0; k0 < K; k0 += 32) {
    // ---- stage A,B tiles: 8 chunks of 1KB each; wave w does chunks w, w+4 ----
#pragma unroll
    for (int i = 0; i < 2; ++i) {
      const int c = w + i * 4;
      const int row = c * 16 + (lane >> 2);            // 0..127
      const int koffb = ((lane & 3) << 4) ^ ((row & 3) << 4);  // swizzled k-byte
      gload16(A + (size_t)(m0 + row) * K + k0 + (koffb >> 1),
              (char*)At + c * 1024 + (lane << 4));
      int rb = n0 + row;
      rb = rb > Nlim ? Nlim : rb;                      // clamp (GEMM2 edge tile)
      gload16(Bt + (size_t)rb * K + k0 + (koffb >> 1),
              (char*)Bs + c * 1024 + (lane << 4));
    }
    __syncthreads();  // drains vmcnt -> LDS writes visible
    f16x8 a[4], b[4];
#pragma unroll
    for (int mi = 0; mi < 4; ++mi) {
      int row = wm * 64 + mi * 16 + fr;
      a[mi] = *(const f16x8*)&At[(row << 5) + (kg ^ ((row & 3) << 3))];
    }
#pragma unroll
    for (int ni = 0; ni < 4; ++ni) {
      int row = wn * 64 + ni * 16 + fr;
      b[ni] = *(const f16x8*)&Bs[(row << 5) + (kg ^ ((row & 3) << 3))];
    }
#pragma unroll
    for (int mi = 0; mi < 4; ++mi)
#pragma unroll
      for (int ni = 0; ni < 4; ++ni)
        acc[mi][ni] = __builtin_amdgcn_mfma_f32_16x16x32_f16(
            a[mi], b[ni], acc[mi][ni], 0, 0, 0);
    __syncthreads();  // protect LDS from next-iter staging
  }

  // ---- epilogue: D col = lane&15, row = (lane>>4)*4 + j ----
  const int r4 = (lane >> 4) << 2;
#pragma unroll
  for (int mi = 0; mi < 4; ++mi) {
#pragma unroll
    for (int ni = 0; ni < 4; ++ni) {
      int col = n0 + wn * 64 + ni * 16 + fr;
      if (col < N) {
        size_t base = (size_t)(m0 + wm * 64 + mi * 16 + r4) * N + col;
#pragma unroll
        for (int j = 0; j < 4; ++j) {
          float v = acc[mi][ni][j];
          if (MODE == 1 && col >= 2 * DS) v = softplusf(v);
          if (MODE == 2) v += R[base + (size_t)j * N];
          C[base + (size_t)j * N] = v;
        }
      }
    }
  }
}

// ------------- causal depthwise conv (k=4) + bias + SiLU -> f16 -------------
__global__ __launch_bounds__(256) void k_conv(
    const float* __restrict__ xz, const float* __restrict__ cw,
    const float* __restrict__ cb, f16* __restrict__ xs) {
  size_t idx = (size_t)blockIdx.x * 256 + threadIdx.x;  // over TOK*DI
  int d = (int)(idx & (DI - 1));
  size_t tf = idx >> 11;                 // flat token b*L + t
  int t = (int)(tf & (LSEQ - 1));
  const float* base = xz + tf * XZW + d;
  float acc = cb[d];
  float w0 = cw[d * 4 + 0], w1 = cw[d * 4 + 1], w2 = cw[d * 4 + 2], w3 = cw[d * 4 + 3];
  acc = fmaf(w3, base[0], acc);
  if (t >= 1) acc = fmaf(w2, *(base - (ptrdiff_t)XZW), acc);
  if (t >= 2) acc = fmaf(w1, *(base - (ptrdiff_t)(2 * XZW)), acc);
  if (t >= 3) acc = fmaf(w0, *(base - (ptrdiff_t)(3 * XZW)), acc);
  xs[idx] = (f16)siluf(acc);
}

// ------------- selective scan: one lane per (b, d, n) -------------
// proj row: [B_in(16) | C_in(16) | delta(2048, softplus already applied)]
__global__ __launch_bounds__(256) void k_scan(
    const float* __restrict__ proj, const f16* __restrict__ xs,
    const float* __restrict__ A_log, float* __restrict__ y) {
  int gid = blockIdx.x * 256 + threadIdx.x;  // 65536 total
  int n = gid & 15;
  int cg = gid >> 4;            // b*DI + d
  int d = cg & (DI - 1);
  int b = cg >> 11;
  float Ad = -__expf(A_log[d * DS + n]);
  float h = 0.f;
  const float* prow = proj + (size_t)b * LSEQ * NPROJ;
  size_t drow = (size_t)b * LSEQ * DI;
#pragma unroll 4
  for (int t = 0; t < LSEQ; ++t) {
    const float* pr = prow + (size_t)t * NPROJ;
    float dt = pr[2 * DS + d];
    float Bn = pr[n];
    float Cn = pr[DS + n];
    float xv = (float)xs[drow + (size_t)t * DI + d];
    float da = __expf(dt * Ad);
    h = fmaf(da, h, (dt * xv) * Bn);
    float part = h * Cn;
    part += __shfl_xor(part, 1, 16);
    part += __shfl_xor(part, 2, 16);
    part += __shfl_xor(part, 4, 16);
    part += __shfl_xor(part, 8, 16);
    if (n == 0) y[drow + (size_t)t * DI + d] = part;
  }
}

// ------------- gate: yg = (f16)((y + D*xs) * silu(z)) -------------
__global__ __launch_bounds__(256) void k_ymid(
    const float* __restrict__ y, const f16* __restrict__ xs,
    const float* __restrict__ xz, const float* __restrict__ Dp,
    f16* __restrict__ yg) {
  size_t idx = (size_t)blockIdx.x * 256 + threadIdx.x;  // over TOK*DI
  int d = (int)(idx & (DI - 1));
  size_t tf = idx >> 11;
  float z = xz[tf * XZW + DI + d];
  yg[idx] = (f16)((y[idx] + Dp[d] * (float)xs[idx]) * siluf(z));
}

extern "C" void kernel_launch(void* const* d_in, const int* in_sizes, int n_in,
                              void* d_out, int out_size, void* d_ws, size_t ws_size,
                              hipStream_t stream) {
  const float* x       = (const float*)d_in[0];
  const float* norm_w  = (const float*)d_in[1];
  const float* w_in    = (const float*)d_in[2];
  const float* conv_w  = (const float*)d_in[3];
  const float* conv_b  = (const float*)d_in[4];
  const float* w_xproj = (const float*)d_in[5];
  const float* A_log   = (const float*)d_in[6];
  const float* D_param = (const float*)d_in[7];
  const float* w_out   = (const float*)d_in[8];
  float* out = (float*)d_out;

  // workspace layout (bytes), ~189 MiB total
  char* ws = (char*)d_ws;
  size_t off = 0;
  float* xz    = (float*)(ws + off); off += (size_t)TOK * XZW * 4;     // 64 MiB
  float* proj  = (float*)(ws + off); off += (size_t)TOK * NPROJ * 4;   // 32.5 MiB
  float* ybuf  = (float*)(ws + off); off += (size_t)TOK * DI * 4;      // 32 MiB
  f16*   h16   = (f16*)(ws + off);   off += (size_t)TOK * HDIM * 2;    // 8 MiB
  f16*   xs16  = (f16*)(ws + off);   off += (size_t)TOK * DI * 2;      // 16 MiB
  f16*   yg16  = (f16*)(ws + off);   off += (size_t)TOK * DI * 2;      // 16 MiB
  f16*   winT  = (f16*)(ws + off);   off += (size_t)XZW * HDIM * 2;    // 8 MiB
  f16*   wxT   = (f16*)(ws + off);   off += (size_t)NPROJ * DI * 2;    // 8.5 MiB
  f16*   woT   = (f16*)(ws + off);   off += (size_t)HDIM * DI * 2;     // 4 MiB

  // 0. weight transpose+cast (f16, [N][K] row-major)
  k_transpose<<<dim3(XZW / 32, HDIM / 32), 256, 0, stream>>>(w_in, winT, HDIM, XZW);
  k_transpose<<<dim3(NPROJ / 32, DI / 32), 256, 0, stream>>>(w_xproj, wxT, DI, NPROJ);
  k_transpose<<<dim3(HDIM / 32, DI / 32), 256, 0, stream>>>(w_out, woT, DI, HDIM);
  // 1. RMSNorm -> h16
  k_rmsnorm<<<TOK, 256, 0, stream>>>(x, norm_w, h16);
  // 2. xz = h @ w_in       (4096x1024 @ 1024x4096, f16 MFMA)
  k_mgemm<0><<<dim3(XZW / 128, TOK / 128), 256, 0, stream>>>(
      h16, winT, xz, nullptr, TOK, XZW, HDIM);
  // 3. xs16 = silu(conv(xz[:, :DI]) + b)
  k_conv<<<(TOK * DI) / 256, 256, 0, stream>>>(xz, conv_w, conv_b, xs16);
  // 4. proj = xs @ w_xproj (softplus on cols>=32), N=2080 -> 17 n-tiles
  k_mgemm<1><<<dim3(17, TOK / 128), 256, 0, stream>>>(
      xs16, wxT, proj, nullptr, TOK, NPROJ, DI);
  // 5. selective scan -> ybuf (fp32)
  k_scan<<<256, 256, 0, stream>>>(proj, xs16, A_log, ybuf);
  // 6. yg16 = (ybuf + D*xs) * silu(z)
  k_ymid<<<(TOK * DI) / 256, 256, 0, stream>>>(ybuf, xs16, xz, D_param, yg16);
  // 7. out = x + yg @ w_out
  k_mgemm<2><<<dim3(HDIM / 128, TOK / 128), 256, 0, stream>>>(
      yg16, woT, out, x, TOK, HDIM, DI);
}

// Round 6
// 632.631 us; speedup vs baseline: 2.0089x; 2.0089x over previous
//
#include <hip/hip_runtime.h>
#include <math.h>

// Problem constants (B=2, L=2048, H=1024, d_inner=2048, d_state=16, d_conv=4)
#define BATCH 2
#define LSEQ  2048
#define HDIM  1024
#define DI    2048
#define DS    16
#define NPROJ 2080          // 2*DS + DI
#define TOK   4096          // BATCH*LSEQ
#define XZW   4096          // 2*DI
#define NCH   32            // scan chunks
#define CLEN  64            // LSEQ / NCH

typedef _Float16 f16;
typedef _Float16 f16x8 __attribute__((ext_vector_type(8)));
typedef _Float16 f16x4 __attribute__((ext_vector_type(4)));
typedef float    f32x4 __attribute__((ext_vector_type(4)));

__device__ __forceinline__ float siluf(float v) { return v / (1.f + __expf(-v)); }
__device__ __forceinline__ float softplusf(float v) {
  return v > 20.f ? v : log1pf(__expf(v));
}

// async global->LDS, 16B per lane. LDS dest must be wave-uniform base + lane*16.
__device__ __forceinline__ void gload16(const void* g, void* l) {
  __builtin_amdgcn_global_load_lds(
      (const __attribute__((address_space(1))) void*)g,
      (__attribute__((address_space(3))) void*)l, 16, 0, 0);
}

// ---------------- weight transpose+cast: Wt[c][r] = (f16)W[r][c] ----------------
__global__ __launch_bounds__(256) void k_transpose(
    const float* __restrict__ W, f16* __restrict__ Wt, int R, int C) {
  __shared__ float t[32][33];
  int c0 = blockIdx.x * 32, r0 = blockIdx.y * 32;
  int tx = threadIdx.x & 31, ty = threadIdx.x >> 5;  // 32 x 8
#pragma unroll
  for (int i = 0; i < 4; ++i) {
    int r = ty + i * 8;
    t[r][tx] = W[(size_t)(r0 + r) * C + c0 + tx];
  }
  __syncthreads();
#pragma unroll
  for (int i = 0; i < 4; ++i) {
    int r = ty + i * 8;  // row in Wt tile (= col in W)
    Wt[(size_t)(c0 + r) * R + r0 + tx] = (f16)t[tx][r];
  }
}

// ---------------- RMSNorm -> f16 ----------------
__global__ __launch_bounds__(256) void k_rmsnorm(
    const float* __restrict__ x, const float* __restrict__ w, f16* __restrict__ h) {
  int t = blockIdx.x;
  int tid = threadIdx.x;
  float4 v = reinterpret_cast<const float4*>(x + (size_t)t * HDIM)[tid];
  float ss = v.x * v.x + v.y * v.y + v.z * v.z + v.w * v.w;
#pragma unroll
  for (int off = 32; off; off >>= 1) ss += __shfl_down(ss, off, 64);
  __shared__ float sred[4];
  if ((tid & 63) == 0) sred[tid >> 6] = ss;
  __syncthreads();
  float tot = sred[0] + sred[1] + sred[2] + sred[3];
  float scale = rsqrtf(tot * (1.f / HDIM) + 1e-6f);
  float4 wv = reinterpret_cast<const float4*>(w)[tid];
  f16x4 o;
  o[0] = (f16)(v.x * scale * wv.x);
  o[1] = (f16)(v.y * scale * wv.y);
  o[2] = (f16)(v.z * scale * wv.z);
  o[3] = (f16)(v.w * scale * wv.w);
  *reinterpret_cast<f16x4*>(h + (size_t)t * HDIM + tid * 4) = o;
}

// ---------------- f16 MFMA GEMM: C[M,N](f32) = A[M,K](f16) @ Bt[N,K](f16)^T ----
// 128x128 tile, BK=32, 4 waves (2x2 of 64x64), 16x16x32 MFMA, 4x4 frags/wave.
// LDS tiles [128 rows][32 k] f16, XOR-swizzled (byte ^= (row&3)<<4) via
// pre-swizzled global source feeding linear global_load_lds (m173 pattern).
// MODE 0: plain store. MODE 1: softplus cols>=32. MODE 2: += R.
template <int MODE>
__global__ __launch_bounds__(256) void k_mgemm(
    const f16* __restrict__ A, const f16* __restrict__ Bt,
    float* __restrict__ C, const float* __restrict__ R,
    int M, int N, int K) {
  __shared__ __align__(16) f16 At[128 * 32];
  __shared__ __align__(16) f16 Bs[128 * 32];
  const int tid = threadIdx.x;
  const int lane = tid & 63;
  const int w = tid >> 6;
  const int wm = w >> 1, wn = w & 1;
  const int m0 = blockIdx.y * 128, n0 = blockIdx.x * 128;
  const int Nlim = N - 1;

  f32x4 acc[4][4];
#pragma unroll
  for (int i = 0; i < 4; ++i)
#pragma unroll
    for (int j = 0; j < 4; ++j) acc[i][j] = (f32x4){0.f, 0.f, 0.f, 0.f};

  const int fr = lane & 15;          // fragment row (A row / Bt row / D col)
  const int kg = (lane >> 4) << 3;   // k element offset: 0/8/16/24

  for (int k0 = 0; k0 < K; k0 += 32) {
    // ---- stage A,B tiles: 8 chunks of 1KB each; wave w does chunks w, w+4 ----
#pragma unroll
    for (int i = 0; i < 2; ++i) {
      const int c = w + i * 4;
      const int row = c * 16 + (lane >> 2);            // 0..127
      const int koffb = ((lane & 3) << 4) ^ ((row & 3) << 4);  // swizzled k-byte
      gload16(A + (size_t)(m0 + row) * K + k0 + (koffb >> 1),
              (char*)At + c * 1024 + (lane << 4));
      int rb = n0 + row;
      rb = rb > Nlim ? Nlim : rb;                      // clamp (GEMM2 edge tile)
      gload16(Bt + (size_t)rb * K + k0 + (koffb >> 1),
              (char*)Bs + c * 1024 + (lane << 4));
    }
    __syncthreads();  // drains vmcnt -> LDS writes visible
    f16x8 a[4], b[4];
#pragma unroll
    for (int mi = 0; mi < 4; ++mi) {
      int row = wm * 64 + mi * 16 + fr;
      a[mi] = *(const f16x8*)&At[(row << 5) + (kg ^ ((row & 3) << 3))];
    }
#pragma unroll
    for (int ni = 0; ni < 4; ++ni) {
      int row = wn * 64 + ni * 16 + fr;
      b[ni] = *(const f16x8*)&Bs[(row << 5) + (kg ^ ((row & 3) << 3))];
    }
#pragma unroll
    for (int mi = 0; mi < 4; ++mi)
#pragma unroll
      for (int ni = 0; ni < 4; ++ni)
        acc[mi][ni] = __builtin_amdgcn_mfma_f32_16x16x32_f16(
            a[mi], b[ni], acc[mi][ni], 0, 0, 0);
    __syncthreads();  // protect LDS from next-iter staging
  }

  // ---- epilogue: D col = lane&15, row = (lane>>4)*4 + j ----
  const int r4 = (lane >> 4) << 2;
#pragma unroll
  for (int mi = 0; mi < 4; ++mi) {
#pragma unroll
    for (int ni = 0; ni < 4; ++ni) {
      int col = n0 + wn * 64 + ni * 16 + fr;
      if (col < N) {
        size_t base = (size_t)(m0 + wm * 64 + mi * 16 + r4) * N + col;
#pragma unroll
        for (int j = 0; j < 4; ++j) {
          float v = acc[mi][ni][j];
          if (MODE == 1 && col >= 2 * DS) v = softplusf(v);
          if (MODE == 2) v += R[base + (size_t)j * N];
          C[base + (size_t)j * N] = v;
        }
      }
    }
  }
}

// ------------- causal depthwise conv (k=4) + bias + SiLU -> f16 -------------
__global__ __launch_bounds__(256) void k_conv(
    const float* __restrict__ xz, const float* __restrict__ cw,
    const float* __restrict__ cb, f16* __restrict__ xs) {
  size_t idx = (size_t)blockIdx.x * 256 + threadIdx.x;  // over TOK*DI
  int d = (int)(idx & (DI - 1));
  size_t tf = idx >> 11;                 // flat token b*L + t
  int t = (int)(tf & (LSEQ - 1));
  const float* base = xz + tf * XZW + d;
  float acc = cb[d];
  float w0 = cw[d * 4 + 0], w1 = cw[d * 4 + 1], w2 = cw[d * 4 + 2], w3 = cw[d * 4 + 3];
  acc = fmaf(w3, base[0], acc);
  if (t >= 1) acc = fmaf(w2, *(base - (ptrdiff_t)XZW), acc);
  if (t >= 2) acc = fmaf(w1, *(base - (ptrdiff_t)(2 * XZW)), acc);
  if (t >= 3) acc = fmaf(w0, *(base - (ptrdiff_t)(3 * XZW)), acc);
  xs[idx] = (f16)siluf(acc);
}

// ======================= chunked parallel selective scan =======================
// h_t = da_t * h_{t-1} + (dt*x)_t * B_t  is linear in h -> split L into NCH
// chunks of CLEN; phase A computes per-chunk (P = prod da, h_end | h_in=0);
// phase B stitches chunk boundary states; phase C re-scans with true h_in and
// emits the gated f16 output directly.
// Buffer layout for all three: idx = ((c*BATCH + b)*DI + d)*DS + n.

// Phase A: 2M threads. gid = c*2^16 + b*2^15 + d*16 + n.
__global__ __launch_bounds__(256) void k_scanA(
    const float* __restrict__ proj, const f16* __restrict__ xs,
    const float* __restrict__ A_log,
    float* __restrict__ Atot, float* __restrict__ Hend) {
  int gid = blockIdx.x * 256 + threadIdx.x;
  int n = gid & 15;
  int d = (gid >> 4) & (DI - 1);
  int b = (gid >> 15) & (BATCH - 1);
  int c = gid >> 16;
  float Ad = -__expf(A_log[d * DS + n]);
  float P = 1.f, h = 0.f;
  const float* prow = proj + ((size_t)b * LSEQ + c * CLEN) * NPROJ;
  const f16* xrow = xs + ((size_t)b * LSEQ + c * CLEN) * DI + d;
#pragma unroll 4
  for (int t = 0; t < CLEN; ++t) {
    const float* pr = prow + (size_t)t * NPROJ;
    float dt = pr[2 * DS + d];
    float Bn = pr[n];
    float xv = (float)xrow[(size_t)t * DI];
    float da = __expf(dt * Ad);
    P *= da;
    h = fmaf(da, h, (dt * xv) * Bn);
  }
  Atot[gid] = P;
  Hend[gid] = h;
}

// Phase B: 65536 threads, sequential stitch over 32 chunks.
__global__ __launch_bounds__(256) void k_scanB(
    const float* __restrict__ Atot, const float* __restrict__ Hend,
    float* __restrict__ Hin) {
  int gid = blockIdx.x * 256 + threadIdx.x;  // (b,d,n)
  float h = 0.f;
#pragma unroll
  for (int c = 0; c < NCH; ++c) {
    size_t idx = (size_t)c * (BATCH * DI * DS) + gid;
    Hin[idx] = h;
    h = fmaf(Atot[idx], h, Hend[idx]);
  }
}

// Phase C: 2M threads; re-scan chunk from Hin, reduce y over n, fuse gate.
__global__ __launch_bounds__(256) void k_scanC(
    const float* __restrict__ proj, const f16* __restrict__ xs,
    const float* __restrict__ xz, const float* __restrict__ A_log,
    const float* __restrict__ Dp, const float* __restrict__ Hin,
    f16* __restrict__ yg) {
  int gid = blockIdx.x * 256 + threadIdx.x;
  int n = gid & 15;
  int d = (gid >> 4) & (DI - 1);
  int b = (gid >> 15) & (BATCH - 1);
  int c = gid >> 16;
  float Ad = -__expf(A_log[d * DS + n]);
  float h = Hin[gid];
  float Dd = Dp[d];
  const float* prow = proj + ((size_t)b * LSEQ + c * CLEN) * NPROJ;
  size_t base = ((size_t)b * LSEQ + c * CLEN) * DI + d;
#pragma unroll 4
  for (int t = 0; t < CLEN; ++t) {
    const float* pr = prow + (size_t)t * NPROJ;
    float dt = pr[2 * DS + d];
    float Bn = pr[n];
    float Cn = pr[DS + n];
    float xv = (float)xs[base + (size_t)t * DI];
    float da = __expf(dt * Ad);
    h = fmaf(da, h, (dt * xv) * Bn);
    float part = h * Cn;
    part += __shfl_xor(part, 1, 16);
    part += __shfl_xor(part, 2, 16);
    part += __shfl_xor(part, 4, 16);
    part += __shfl_xor(part, 8, 16);
    if (n == 0) {
      float z = xz[((size_t)b * LSEQ + c * CLEN + t) * XZW + DI + d];
      yg[base + (size_t)t * DI] = (f16)((part + Dd * xv) * siluf(z));
    }
  }
}

extern "C" void kernel_launch(void* const* d_in, const int* in_sizes, int n_in,
                              void* d_out, int out_size, void* d_ws, size_t ws_size,
                              hipStream_t stream) {
  const float* x       = (const float*)d_in[0];
  const float* norm_w  = (const float*)d_in[1];
  const float* w_in    = (const float*)d_in[2];
  const float* conv_w  = (const float*)d_in[3];
  const float* conv_b  = (const float*)d_in[4];
  const float* w_xproj = (const float*)d_in[5];
  const float* A_log   = (const float*)d_in[6];
  const float* D_param = (const float*)d_in[7];
  const float* w_out   = (const float*)d_in[8];
  float* out = (float*)d_out;

  // workspace layout (bytes), ~181 MiB total
  char* ws = (char*)d_ws;
  size_t off = 0;
  float* xz    = (float*)(ws + off); off += (size_t)TOK * XZW * 4;       // 64 MiB
  float* proj  = (float*)(ws + off); off += (size_t)TOK * NPROJ * 4;     // 32.5 MiB
  f16*   h16   = (f16*)(ws + off);   off += (size_t)TOK * HDIM * 2;      // 8 MiB
  f16*   xs16  = (f16*)(ws + off);   off += (size_t)TOK * DI * 2;        // 16 MiB
  f16*   yg16  = (f16*)(ws + off);   off += (size_t)TOK * DI * 2;        // 16 MiB
  f16*   winT  = (f16*)(ws + off);   off += (size_t)XZW * HDIM * 2;      // 8 MiB
  f16*   wxT   = (f16*)(ws + off);   off += (size_t)NPROJ * DI * 2;      // 8.5 MiB
  f16*   woT   = (f16*)(ws + off);   off += (size_t)HDIM * DI * 2;       // 4 MiB
  const size_t SCN = (size_t)NCH * BATCH * DI * DS;                      // 2M elems
  float* Atot  = (float*)(ws + off); off += SCN * 4;                     // 8 MiB
  float* Hend  = (float*)(ws + off); off += SCN * 4;                     // 8 MiB
  float* Hin   = (float*)(ws + off); off += SCN * 4;                     // 8 MiB

  // 0. weight transpose+cast (f16, [N][K] row-major)
  k_transpose<<<dim3(XZW / 32, HDIM / 32), 256, 0, stream>>>(w_in, winT, HDIM, XZW);
  k_transpose<<<dim3(NPROJ / 32, DI / 32), 256, 0, stream>>>(w_xproj, wxT, DI, NPROJ);
  k_transpose<<<dim3(HDIM / 32, DI / 32), 256, 0, stream>>>(w_out, woT, DI, HDIM);
  // 1. RMSNorm -> h16
  k_rmsnorm<<<TOK, 256, 0, stream>>>(x, norm_w, h16);
  // 2. xz = h @ w_in       (4096x1024 @ 1024x4096, f16 MFMA)
  k_mgemm<0><<<dim3(XZW / 128, TOK / 128), 256, 0, stream>>>(
      h16, winT, xz, nullptr, TOK, XZW, HDIM);
  // 3. xs16 = silu(conv(xz[:, :DI]) + b)
  k_conv<<<(TOK * DI) / 256, 256, 0, stream>>>(xz, conv_w, conv_b, xs16);
  // 4. proj = xs @ w_xproj (softplus on cols>=32), N=2080 -> 17 n-tiles
  k_mgemm<1><<<dim3(17, TOK / 128), 256, 0, stream>>>(
      xs16, wxT, proj, nullptr, TOK, NPROJ, DI);
  // 5. chunked scan: A (per-chunk), B (stitch), C (re-scan + gate -> yg16)
  k_scanA<<<(int)(SCN / 256), 256, 0, stream>>>(proj, xs16, A_log, Atot, Hend);
  k_scanB<<<(BATCH * DI * DS) / 256, 256, 0, stream>>>(Atot, Hend, Hin);
  k_scanC<<<(int)(SCN / 256), 256, 0, stream>>>(proj, xs16, xz, A_log, D_param,
                                                Hin, yg16);
  // 6. out = x + yg @ w_out
  k_mgemm<2><<<dim3(HDIM / 128, TOK / 128), 256, 0, stream>>>(
      yg16, woT, out, x, TOK, HDIM, DI);
}

// Round 9
// 461.744 us; speedup vs baseline: 2.7524x; 1.3701x over previous
//
#include <hip/hip_runtime.h>
#include <math.h>

// Problem constants (B=2, L=2048, H=1024, d_inner=2048, d_state=16, d_conv=4)
#define BATCH 2
#define LSEQ  2048
#define HDIM  1024
#define DI    2048
#define DS    16
#define NPROJ 2080          // 2*DS + DI
#define TOK   4096          // BATCH*LSEQ
#define XZW   4096          // 2*DI
#define NCH   64            // scan chunks
#define CLEN  32            // LSEQ / NCH

typedef _Float16 f16;
typedef _Float16 f16x8 __attribute__((ext_vector_type(8)));
typedef _Float16 f16x4 __attribute__((ext_vector_type(4)));
typedef float    f32x4 __attribute__((ext_vector_type(4)));

__device__ __forceinline__ float siluf(float v) { return v / (1.f + __expf(-v)); }
__device__ __forceinline__ float softplusf(float v) {
  return v > 20.f ? v : log1pf(__expf(v));
}

// async global->LDS, 16B per lane. LDS dest must be wave-uniform base + lane*16.
__device__ __forceinline__ void gload16(const void* g, void* l) {
  __builtin_amdgcn_global_load_lds(
      (const __attribute__((address_space(1))) void*)g,
      (__attribute__((address_space(3))) void*)l, 16, 0, 0);
}

// ---------------- weight transpose+cast: Wt[c][r] = (f16)W[r][c] ----------------
__global__ __launch_bounds__(256) void k_transpose(
    const float* __restrict__ W, f16* __restrict__ Wt, int R, int C) {
  __shared__ float t[32][33];
  int c0 = blockIdx.x * 32, r0 = blockIdx.y * 32;
  int tx = threadIdx.x & 31, ty = threadIdx.x >> 5;  // 32 x 8
#pragma unroll
  for (int i = 0; i < 4; ++i) {
    int r = ty + i * 8;
    t[r][tx] = W[(size_t)(r0 + r) * C + c0 + tx];
  }
  __syncthreads();
#pragma unroll
  for (int i = 0; i < 4; ++i) {
    int r = ty + i * 8;  // row in Wt tile (= col in W)
    Wt[(size_t)(c0 + r) * R + r0 + tx] = (f16)t[tx][r];
  }
}

// ---------------- RMSNorm -> f16 ----------------
__global__ __launch_bounds__(256) void k_rmsnorm(
    const float* __restrict__ x, const float* __restrict__ w, f16* __restrict__ h) {
  int t = blockIdx.x;
  int tid = threadIdx.x;
  float4 v = reinterpret_cast<const float4*>(x + (size_t)t * HDIM)[tid];
  float ss = v.x * v.x + v.y * v.y + v.z * v.z + v.w * v.w;
#pragma unroll
  for (int off = 32; off; off >>= 1) ss += __shfl_down(ss, off, 64);
  __shared__ float sred[4];
  if ((tid & 63) == 0) sred[tid >> 6] = ss;
  __syncthreads();
  float tot = sred[0] + sred[1] + sred[2] + sred[3];
  float scale = rsqrtf(tot * (1.f / HDIM) + 1e-6f);
  float4 wv = reinterpret_cast<const float4*>(w)[tid];
  f16x4 o;
  o[0] = (f16)(v.x * scale * wv.x);
  o[1] = (f16)(v.y * scale * wv.y);
  o[2] = (f16)(v.z * scale * wv.z);
  o[3] = (f16)(v.w * scale * wv.w);
  *reinterpret_cast<f16x4*>(h + (size_t)t * HDIM + tid * 4) = o;
}

// ---------------- f16 MFMA GEMM: C[M,N](f32) = A[M,K](f16) @ Bt[N,K](f16)^T ----
// 128x128 tile, BK=32, 4 waves (2x2 of 64x64), 16x16x32 MFMA, 4x4 frags/wave.
// MODE 0: plain store. MODE 1: softplus cols>=32. MODE 2: += R.
template <int MODE>
__global__ __launch_bounds__(256) void k_mgemm(
    const f16* __restrict__ A, const f16* __restrict__ Bt,
    float* __restrict__ C, const float* __restrict__ R,
    int M, int N, int K) {
  __shared__ __align__(16) f16 At[128 * 32];
  __shared__ __align__(16) f16 Bs[128 * 32];
  const int tid = threadIdx.x;
  const int lane = tid & 63;
  const int w = tid >> 6;
  const int wm = w >> 1, wn = w & 1;
  const int m0 = blockIdx.y * 128, n0 = blockIdx.x * 128;
  const int Nlim = N - 1;

  f32x4 acc[4][4];
#pragma unroll
  for (int i = 0; i < 4; ++i)
#pragma unroll
    for (int j = 0; j < 4; ++j) acc[i][j] = (f32x4){0.f, 0.f, 0.f, 0.f};

  const int fr = lane & 15;          // fragment row (A row / Bt row / D col)
  const int kg = (lane >> 4) << 3;   // k element offset: 0/8/16/24

  for (int k0 = 0; k0 < K; k0 += 32) {
    // ---- stage A,B tiles: 8 chunks of 1KB each; wave w does chunks w, w+4 ----
#pragma unroll
    for (int i = 0; i < 2; ++i) {
      const int c = w + i * 4;
      const int row = c * 16 + (lane >> 2);            // 0..127
      const int koffb = ((lane & 3) << 4) ^ ((row & 3) << 4);  // swizzled k-byte
      gload16(A + (size_t)(m0 + row) * K + k0 + (koffb >> 1),
              (char*)At + c * 1024 + (lane << 4));
      int rb = n0 + row;
      rb = rb > Nlim ? Nlim : rb;                      // clamp (GEMM2 edge tile)
      gload16(Bt + (size_t)rb * K + k0 + (koffb >> 1),
              (char*)Bs + c * 1024 + (lane << 4));
    }
    __syncthreads();  // drains vmcnt -> LDS writes visible
    f16x8 a[4], b[4];
#pragma unroll
    for (int mi = 0; mi < 4; ++mi) {
      int row = wm * 64 + mi * 16 + fr;
      a[mi] = *(const f16x8*)&At[(row << 5) + (kg ^ ((row & 3) << 3))];
    }
#pragma unroll
    for (int ni = 0; ni < 4; ++ni) {
      int row = wn * 64 + ni * 16 + fr;
      b[ni] = *(const f16x8*)&Bs[(row << 5) + (kg ^ ((row & 3) << 3))];
    }
#pragma unroll
    for (int mi = 0; mi < 4; ++mi)
#pragma unroll
      for (int ni = 0; ni < 4; ++ni)
        acc[mi][ni] = __builtin_amdgcn_mfma_f32_16x16x32_f16(
            a[mi], b[ni], acc[mi][ni], 0, 0, 0);
    __syncthreads();  // protect LDS from next-iter staging
  }

  // ---- epilogue: D col = lane&15, row = (lane>>4)*4 + j ----
  const int r4 = (lane >> 4) << 2;
#pragma unroll
  for (int mi = 0; mi < 4; ++mi) {
#pragma unroll
    for (int ni = 0; ni < 4; ++ni) {
      int col = n0 + wn * 64 + ni * 16 + fr;
      if (col < N) {
        size_t base = (size_t)(m0 + wm * 64 + mi * 16 + r4) * N + col;
#pragma unroll
        for (int j = 0; j < 4; ++j) {
          float v = acc[mi][ni][j];
          if (MODE == 1 && col >= 2 * DS) v = softplusf(v);
          if (MODE == 2) v += R[base + (size_t)j * N];
          C[base + (size_t)j * N] = v;
        }
      }
    }
  }
}

// ------------- causal depthwise conv (k=4) + bias + SiLU -> f16 -------------
__global__ __launch_bounds__(256) void k_conv(
    const float* __restrict__ xz, const float* __restrict__ cw,
    const float* __restrict__ cb, f16* __restrict__ xs) {
  size_t idx = (size_t)blockIdx.x * 256 + threadIdx.x;  // over TOK*DI
  int d = (int)(idx & (DI - 1));
  size_t tf = idx >> 11;                 // flat token b*L + t
  int t = (int)(tf & (LSEQ - 1));
  const float* base = xz + tf * XZW + d;
  float acc = cb[d];
  float w0 = cw[d * 4 + 0], w1 = cw[d * 4 + 1], w2 = cw[d * 4 + 2], w3 = cw[d * 4 + 3];
  acc = fmaf(w3, base[0], acc);
  if (t >= 1) acc = fmaf(w2, *(base - (ptrdiff_t)XZW), acc);
  if (t >= 2) acc = fmaf(w1, *(base - (ptrdiff_t)(2 * XZW)), acc);
  if (t >= 3) acc = fmaf(w0, *(base - (ptrdiff_t)(3 * XZW)), acc);
  xs[idx] = (f16)siluf(acc);
}

// ======================= chunked parallel selective scan =======================
// Thread per (b,d,chunk); all DS=16 states in registers. Lanes = consecutive d
// -> dt/xv loads coalesced, B/C row loads wave-uniform (broadcast).
// State buffers layout: idx = ((c*BATCH + b)*DI + d)*DS + n = gid*DS + n.

// Phase A: per-chunk scan from h=0; emit P[n] = prod(da), h_end[n].
__global__ __launch_bounds__(256) void k_scanA(
    const float* __restrict__ proj, const f16* __restrict__ xs,
    const float* __restrict__ A_log,
    float* __restrict__ Atot, float* __restrict__ Hend) {
  int gid = blockIdx.x * 256 + threadIdx.x;   // (c*BATCH+b)*DI + d
  int d = gid & (DI - 1);
  int b = (gid >> 11) & (BATCH - 1);
  int c = gid >> 12;
  float Ad[DS];
  {
    const float4* ap = reinterpret_cast<const float4*>(A_log + (size_t)d * DS);
#pragma unroll
    for (int i = 0; i < 4; ++i) {
      float4 v = ap[i];
      Ad[4 * i + 0] = -__expf(v.x);
      Ad[4 * i + 1] = -__expf(v.y);
      Ad[4 * i + 2] = -__expf(v.z);
      Ad[4 * i + 3] = -__expf(v.w);
    }
  }
  float h[DS], P[DS];
#pragma unroll
  for (int n = 0; n < DS; ++n) { h[n] = 0.f; P[n] = 1.f; }
  const float* prow = proj + ((size_t)b * LSEQ + (size_t)c * CLEN) * NPROJ;
  const f16* xrow = xs + ((size_t)b * LSEQ + (size_t)c * CLEN) * DI + d;
  for (int t = 0; t < CLEN; ++t) {
    const float* pr = prow + (size_t)t * NPROJ;
    float dt = pr[2 * DS + d];
    float xv = (float)xrow[(size_t)t * DI];
    float Bv[DS];
    {
      const float4* p4 = reinterpret_cast<const float4*>(pr);
#pragma unroll
      for (int i = 0; i < 4; ++i) {
        float4 v = p4[i];
        Bv[4 * i + 0] = v.x; Bv[4 * i + 1] = v.y;
        Bv[4 * i + 2] = v.z; Bv[4 * i + 3] = v.w;
      }
    }
    float dxv = dt * xv;
#pragma unroll
    for (int n = 0; n < DS; ++n) {
      float da = __expf(dt * Ad[n]);
      P[n] *= da;
      h[n] = fmaf(da, h[n], dxv * Bv[n]);
    }
  }
  float4* ao = reinterpret_cast<float4*>(Atot + (size_t)gid * DS);
  float4* ho = reinterpret_cast<float4*>(Hend + (size_t)gid * DS);
#pragma unroll
  for (int i = 0; i < 4; ++i) {
    ao[i] = make_float4(P[4 * i], P[4 * i + 1], P[4 * i + 2], P[4 * i + 3]);
    ho[i] = make_float4(h[4 * i], h[4 * i + 1], h[4 * i + 2], h[4 * i + 3]);
  }
}

// Phase B: sequential stitch over chunks; writes Hin IN PLACE over Atot.
__global__ __launch_bounds__(256) void k_scanB(
    float* __restrict__ Atot, const float* __restrict__ Hend) {
  int gid = blockIdx.x * 256 + threadIdx.x;  // (b*DI+d)*DS + n, 65536 total
  float h = 0.f;
#pragma unroll
  for (int c = 0; c < NCH; ++c) {
    size_t idx = (size_t)c * (BATCH * DI * DS) + gid;
    float P = Atot[idx];
    Atot[idx] = h;                 // h_in for chunk c
    h = fmaf(P, h, Hend[idx]);
  }
}

// Phase C: re-scan chunk from Hin (in Atot buffer), reduce over n, fuse gate.
__global__ __launch_bounds__(256) void k_scanC(
    const float* __restrict__ proj, const f16* __restrict__ xs,
    const float* __restrict__ xz, const float* __restrict__ A_log,
    const float* __restrict__ Dp, const float* __restrict__ Hin,
    f16* __restrict__ yg) {
  int gid = blockIdx.x * 256 + threadIdx.x;   // (c*BATCH+b)*DI + d
  int d = gid & (DI - 1);
  int b = (gid >> 11) & (BATCH - 1);
  int c = gid >> 12;
  float Ad[DS];
  {
    const float4* ap = reinterpret_cast<const float4*>(A_log + (size_t)d * DS);
#pragma unroll
    for (int i = 0; i < 4; ++i) {
      float4 v = ap[i];
      Ad[4 * i + 0] = -__expf(v.x);
      Ad[4 * i + 1] = -__expf(v.y);
      Ad[4 * i + 2] = -__expf(v.z);
      Ad[4 * i + 3] = -__expf(v.w);
    }
  }
  float h[DS];
  {
    const float4* hi = reinterpret_cast<const float4*>(Hin + (size_t)gid * DS);
#pragma unroll
    for (int i = 0; i < 4; ++i) {
      float4 v = hi[i];
      h[4 * i + 0] = v.x; h[4 * i + 1] = v.y;
      h[4 * i + 2] = v.z; h[4 * i + 3] = v.w;
    }
  }
  float Dd = Dp[d];
  const float* prow = proj + ((size_t)b * LSEQ + (size_t)c * CLEN) * NPROJ;
  const f16* xrow = xs + ((size_t)b * LSEQ + (size_t)c * CLEN) * DI + d;
  const float* zrow = xz + ((size_t)b * LSEQ + (size_t)c * CLEN) * XZW + DI + d;
  f16* yrow = yg + ((size_t)b * LSEQ + (size_t)c * CLEN) * DI + d;
  for (int t = 0; t < CLEN; ++t) {
    const float* pr = prow + (size_t)t * NPROJ;
    float dt = pr[2 * DS + d];
    float xv = (float)xrow[(size_t)t * DI];
    float Bv[DS], Cv[DS];
    {
      const float4* p4 = reinterpret_cast<const float4*>(pr);
#pragma unroll
      for (int i = 0; i < 4; ++i) {
        float4 v = p4[i];
        Bv[4 * i + 0] = v.x; Bv[4 * i + 1] = v.y;
        Bv[4 * i + 2] = v.z; Bv[4 * i + 3] = v.w;
      }
#pragma unroll
      for (int i = 0; i < 4; ++i) {
        float4 v = p4[4 + i];
        Cv[4 * i + 0] = v.x; Cv[4 * i + 1] = v.y;
        Cv[4 * i + 2] = v.z; Cv[4 * i + 3] = v.w;
      }
    }
    float dxv = dt * xv;
    float y = 0.f;
#pragma unroll
    for (int n = 0; n < DS; ++n) {
      float da = __expf(dt * Ad[n]);
      h[n] = fmaf(da, h[n], dxv * Bv[n]);
      y = fmaf(h[n], Cv[n], y);
    }
    float z = zrow[(size_t)t * XZW];
    yrow[(size_t)t * DI] = (f16)((y + Dd * xv) * siluf(z));
  }
}

extern "C" void kernel_launch(void* const* d_in, const int* in_sizes, int n_in,
                              void* d_out, int out_size, void* d_ws, size_t ws_size,
                              hipStream_t stream) {
  const float* x       = (const float*)d_in[0];
  const float* norm_w  = (const float*)d_in[1];
  const float* w_in    = (const float*)d_in[2];
  const float* conv_w  = (const float*)d_in[3];
  const float* conv_b  = (const float*)d_in[4];
  const float* w_xproj = (const float*)d_in[5];
  const float* A_log   = (const float*)d_in[6];
  const float* D_param = (const float*)d_in[7];
  const float* w_out   = (const float*)d_in[8];
  float* out = (float*)d_out;

  // workspace layout (bytes), ~189 MiB total (proven-safe size)
  char* ws = (char*)d_ws;
  size_t off = 0;
  float* xz    = (float*)(ws + off); off += (size_t)TOK * XZW * 4;       // 64 MiB
  float* proj  = (float*)(ws + off); off += (size_t)TOK * NPROJ * 4;     // 32.5 MiB
  f16*   h16   = (f16*)(ws + off);   off += (size_t)TOK * HDIM * 2;      // 8 MiB
  f16*   xs16  = (f16*)(ws + off);   off += (size_t)TOK * DI * 2;        // 16 MiB
  f16*   yg16  = (f16*)(ws + off);   off += (size_t)TOK * DI * 2;        // 16 MiB
  f16*   winT  = (f16*)(ws + off);   off += (size_t)XZW * HDIM * 2;      // 8 MiB
  f16*   wxT   = (f16*)(ws + off);   off += (size_t)NPROJ * DI * 2;      // 8.5 MiB
  f16*   woT   = (f16*)(ws + off);   off += (size_t)HDIM * DI * 2;       // 4 MiB
  const size_t SCN = (size_t)NCH * BATCH * DI * DS;                      // 4M elems
  float* Atot  = (float*)(ws + off); off += SCN * 4;                     // 16 MiB (->Hin)
  float* Hend  = (float*)(ws + off); off += SCN * 4;                     // 16 MiB

  // 0. weight transpose+cast (f16, [N][K] row-major)
  k_transpose<<<dim3(XZW / 32, HDIM / 32), 256, 0, stream>>>(w_in, winT, HDIM, XZW);
  k_transpose<<<dim3(NPROJ / 32, DI / 32), 256, 0, stream>>>(w_xproj, wxT, DI, NPROJ);
  k_transpose<<<dim3(HDIM / 32, DI / 32), 256, 0, stream>>>(w_out, woT, DI, HDIM);
  // 1. RMSNorm -> h16
  k_rmsnorm<<<TOK, 256, 0, stream>>>(x, norm_w, h16);
  // 2. xz = h @ w_in       (4096x1024 @ 1024x4096, f16 MFMA)
  k_mgemm<0><<<dim3(XZW / 128, TOK / 128), 256, 0, stream>>>(
      h16, winT, xz, nullptr, TOK, XZW, HDIM);
  // 3. xs16 = silu(conv(xz[:, :DI]) + b)
  k_conv<<<(TOK * DI) / 256, 256, 0, stream>>>(xz, conv_w, conv_b, xs16);
  // 4. proj = xs @ w_xproj (softplus on cols>=32), N=2080 -> 17 n-tiles
  k_mgemm<1><<<dim3(17, TOK / 128), 256, 0, stream>>>(
      xs16, wxT, proj, nullptr, TOK, NPROJ, DI);
  // 5. chunked scan: A (per-chunk, reg-state), B (in-place stitch), C (+gate)
  const int NTH = NCH * BATCH * DI;                     // 262144 threads
  k_scanA<<<NTH / 256, 256, 0, stream>>>(proj, xs16, A_log, Atot, Hend);
  k_scanB<<<(BATCH * DI * DS) / 256, 256, 0, stream>>>(Atot, Hend);
  k_scanC<<<NTH / 256, 256, 0, stream>>>(proj, xs16, xz, A_log, D_param,
                                         Atot, yg16);
  // 6. out = x + yg @ w_out
  k_mgemm<2><<<dim3(HDIM / 128, TOK / 128), 256, 0, stream>>>(
      yg16, woT, out, x, TOK, HDIM, DI);
}